// Round 13
// baseline (240.539 us; speedup 1.0000x reference)
//
#include <hip/hip_runtime.h>
#include <stdint.h>
#include <stddef.h>

#define KH   512
#define DF   3072
#define EPSF 1e-5f
#define PPB  16           // positions per block
#define ROWS 96           // PPB*6
#define TSS  516          // Ts row stride (floats), padded

typedef __attribute__((ext_vector_type(4))) float f32x4;
typedef __attribute__((ext_vector_type(2))) float f32x2;
typedef __attribute__((ext_vector_type(8))) short bf16x8;

__device__ __forceinline__ unsigned short f2bf(float f) {
  union { float f; unsigned u; } c; c.f = f;
  unsigned u = c.u;
  u += 0x7fffu + ((u >> 16) & 1u);     // RNE
  return (unsigned short)(u >> 16);
}
__device__ __forceinline__ unsigned short f2bf_trunc(float f) {
  union { float f; unsigned u; } c; c.f = f;
  return (unsigned short)(c.u >> 16);  // truncation: 1 op
}
__device__ __forceinline__ float bf2f(unsigned short u) {
  union { unsigned u; float f; } c; c.u = ((unsigned)u) << 16;
  return c.f;
}

// Weight images (verified R5 layout): region A (0): alpha*gamma,
// region B (+512KB): beta_w*gamma.
// byte(f,s) = (f>>2)*65536 + s*4096 + (f&3)*1024 + (h*16+co)*16 + e*2, f = o>>4.
// Per-wave per-step fragment read = coalesced 1KB dwordx4 per fragment.
__global__ __launch_bounds__(256) void prep_w(const float* __restrict__ cw,
                                              const float* __restrict__ cb,
                                              const float* __restrict__ nw,
                                              const float* __restrict__ nb,
                                              unsigned char* __restrict__ wbt,
                                              float* __restrict__ c12) {
  const int o = blockIdx.x;
  const int t = threadIdx.x;
  const int wn = o >> 6, nn = (o >> 4) & 3, co = o & 15;
  float c1 = 0.f, c2 = 0.f;
  for (int k = t; k < KH; k += 256) {
    float w0 = cw[o * 1024 + 2 * k];
    float w1 = cw[o * 1024 + 2 * k + 1];
    float a  = w0 - w1;
    float g  = nw[k], b = nb[k];
    int s = k >> 5, kin = k & 31, h = kin >> 3, e = kin & 7;
    size_t base = (size_t)(((wn * 16 + s) * 4 + nn)) * 1024 + (h * 16 + co) * 16 + e * 2;
    *(unsigned short*)(wbt + base)          = f2bf(a * g);    // alpha*gamma
    *(unsigned short*)(wbt + base + 524288) = f2bf(w1 * g);   // beta_w*gamma
    float tt = a + 6.f * w1;
    c1 += tt * b;
    c2 += tt * g;
  }
  #pragma unroll
  for (int off = 32; off >= 1; off >>= 1) {
    c1 += __shfl_xor(c1, off);
    c2 += __shfl_xor(c2, off);
  }
  __shared__ float s1[4], s2[4];
  int wid = t >> 6, lane = t & 63;
  if (lane == 0) { s1[wid] = c1; s2[wid] = c2; }
  __syncthreads();
  if (t == 0) {
    c12[o]      = s1[0] + s1[1] + s1[2] + s1[3] + cb[o];
    c12[KH + o] = s2[0] + s2[1] + s2[2] + s2[3];
  }
}

// Block: 16 positions (96 rows) x 512 o. 1024 threads = 16 waves.
// Wave wid: position wid (prologue); GEMM tile (wm=wid>>3, wn=wid&7) 48x64;
// term2 o-slice wid*32. Two barriers (post-prologue, pre-epilogue).
// LDS ~144.5 KB -> 1 block/CU; B-L2 traffic halved vs PPB=8.
__global__ __launch_bounds__(1024, 4) void fused_main(
    const float* __restrict__ x,
    const unsigned char* __restrict__ wbt,
    const float* __restrict__ c12,
    float* __restrict__ out)
{
  __shared__ unsigned char As[ROWS * 1024];   // 96 KB raw-x panel (bf16, swizzled)
  __shared__ unsigned char Sx[PPB * 1024];    // 16 KB raw color-sum panel
  __shared__ float Ts[PPB * TSS];             // 33 KB term2 (f32)
  __shared__ float st[PPB * 2];

  const int tid  = threadIdx.x;
  const int lane = tid & 63;
  const int wid  = tid >> 6;     // 0..15
  const int wm   = wid >> 3;     // 0..1
  const int wn   = wid & 7;      // 0..7
  const int co   = lane & 15;
  const int h    = lane >> 4;
  const int rvb  = h << 2;
  const size_t r0 = (size_t)blockIdx.x * PPB;

  const unsigned char* wA = wbt + (size_t)wn * 65536;
  bf16x8 bvA[4], bvB[4];

  // ---- fused prologue: wave wid owns position r0+wid ----
  {
    const float* xr = x + (size_t)(r0 + wid) * DF + lane * 48;
    f32x4 q[12];
    #pragma unroll
    for (int i = 0; i < 12; i++) q[i] = *(const f32x4*)(xr + i * 4);

    // prefetch term1's step-0 B fragments (hides L2 latency across barrier)
    #pragma unroll
    for (int n = 0; n < 4; n++)
      bvA[n] = *(const bf16x8*)(wA + n * 1024 + lane * 16);

    float vv[48];
    #pragma unroll
    for (int i = 0; i < 12; i++) {
      vv[4 * i] = q[i].x; vv[4 * i + 1] = q[i].y;
      vv[4 * i + 2] = q[i].z; vv[4 * i + 3] = q[i].w;
    }
    float s = 0.f, sq = 0.f;
    #pragma unroll
    for (int i = 0; i < 48; i++) { s += vv[i]; sq += vv[i] * vv[i]; }
    #pragma unroll
    for (int off = 32; off >= 1; off >>= 1) {
      s  += __shfl_xor(s,  off);
      sq += __shfl_xor(sq, off);
    }
    float mean = s * (1.f / 3072.f);
    float var  = sq * (1.f / 3072.f) - mean * mean;
    float rstd = rsqrtf(var + EPSF);
    if (lane == 0) { st[2 * wid] = mean; st[2 * wid + 1] = rstd; }

    // As rows: lane holds k = lane*8..+8 for all 6 colors -> one b128 per row
    #pragma unroll
    for (int d = 0; d < 6; d++) {
      int row = wid * 6 + d;
      bf16x8 v;
      #pragma unroll
      for (int g = 0; g < 8; g++) v[g] = (short)f2bf_trunc(vv[g * 6 + d]);
      *(bf16x8*)(As + row * 1024 + ((lane ^ (row & 7)) << 4)) = v;
    }
    // Sx: raw color sums for the same 8 k
    bf16x8 sv;
    #pragma unroll
    for (int g = 0; g < 8; g++) {
      float ss = vv[g * 6] + vv[g * 6 + 1] + vv[g * 6 + 2] +
                 vv[g * 6 + 3] + vv[g * 6 + 4] + vv[g * 6 + 5];
      sv[g] = (short)f2bf_trunc(ss);
    }
    *(bf16x8*)(Sx + wid * 1024 + ((lane ^ (wid & 7)) << 4)) = sv;
  }
  __syncthreads();               // B1: As + Sx + st ready

  // ---- term1: 48x64 tile over K=512; A and B register double-buffered ----
  f32x4 acc1[3][4];
  #pragma unroll
  for (int m = 0; m < 3; m++)
    #pragma unroll
    for (int n = 0; n < 4; n++) acc1[m][n] = (f32x4){0.f, 0.f, 0.f, 0.f};

  int arow[3], ar7[3];
  #pragma unroll
  for (int m = 0; m < 3; m++) {
    int row = wm * 48 + m * 16 + co;
    arow[m] = row * 1024;  ar7[m] = row & 7;
  }

  {
    bf16x8 afA[3], afB[3];
    #pragma unroll
    for (int m = 0; m < 3; m++)               // step-0 A fragments
      afA[m] = *(const bf16x8*)(As + arow[m] + ((h ^ ar7[m]) << 4));

    #pragma unroll 1
    for (int s = 0; s < 16; s += 2) {
      {
        int g6 = (s + 1) * 4 + h;
        #pragma unroll
        for (int m = 0; m < 3; m++)
          afB[m] = *(const bf16x8*)(As + arow[m] + ((g6 ^ ar7[m]) << 4));
        const unsigned char* pn = wA + (size_t)(s + 1) * 4096;
        #pragma unroll
        for (int n = 0; n < 4; n++)
          bvB[n] = *(const bf16x8*)(pn + n * 1024 + lane * 16);
      }
      __builtin_amdgcn_s_setprio(1);
      #pragma unroll
      for (int m = 0; m < 3; m++)
        #pragma unroll
        for (int n = 0; n < 4; n++)
          acc1[m][n] = __builtin_amdgcn_mfma_f32_16x16x32_bf16(afA[m], bvA[n], acc1[m][n], 0, 0, 0);
      __builtin_amdgcn_s_setprio(0);
      if (s + 2 < 16) {
        int g6 = (s + 2) * 4 + h;
        #pragma unroll
        for (int m = 0; m < 3; m++)
          afA[m] = *(const bf16x8*)(As + arow[m] + ((g6 ^ ar7[m]) << 4));
        const unsigned char* pn2 = wA + (size_t)(s + 2) * 4096;
        #pragma unroll
        for (int n = 0; n < 4; n++)
          bvA[n] = *(const bf16x8*)(pn2 + n * 1024 + lane * 16);
      }
      __builtin_amdgcn_s_setprio(1);
      #pragma unroll
      for (int m = 0; m < 3; m++)
        #pragma unroll
        for (int n = 0; n < 4; n++)
          acc1[m][n] = __builtin_amdgcn_mfma_f32_16x16x32_bf16(afB[m], bvB[n], acc1[m][n], 0, 0, 0);
      __builtin_amdgcn_s_setprio(0);
    }
  }

  // ---- term2: 16x32 slice over K=512; o-slice wid*32 -> Ts ----
  {
    f32x4 acc2[2];
    acc2[0] = (f32x4){0.f, 0.f, 0.f, 0.f};
    acc2[1] = (f32x4){0.f, 0.f, 0.f, 0.f};
    // fragments f0 = 2*wid, f1 = 2*wid+1:
    // byte(f,s) = (f>>2)*65536 + s*4096 + (f&3)*1024 + lane*16
    const unsigned char* wB2 = wbt + 524288 + (size_t)(wid >> 1) * 65536
                             + (size_t)(2 * (wid & 1)) * 1024 + (size_t)lane * 16;
    const int sxr = co;            // Sx row = position (all 16 valid at PPB=16)
    const int sx7 = sxr & 7;
    bf16x8 cA[2], cB[2];
    bf16x8 a2A, a2B;
    cA[0] = *(const bf16x8*)(wB2);
    cA[1] = *(const bf16x8*)(wB2 + 1024);
    a2A = *(const bf16x8*)(Sx + sxr * 1024 + ((h ^ sx7) << 4));

    #pragma unroll 1
    for (int s = 0; s < 16; s += 2) {
      {
        int g6 = (s + 1) * 4 + h;
        a2B = *(const bf16x8*)(Sx + sxr * 1024 + ((g6 ^ sx7) << 4));
        const unsigned char* pn = wB2 + (size_t)(s + 1) * 4096;
        cB[0] = *(const bf16x8*)(pn);
        cB[1] = *(const bf16x8*)(pn + 1024);
      }
      __builtin_amdgcn_s_setprio(1);
      acc2[0] = __builtin_amdgcn_mfma_f32_16x16x32_bf16(a2A, cA[0], acc2[0], 0, 0, 0);
      acc2[1] = __builtin_amdgcn_mfma_f32_16x16x32_bf16(a2A, cA[1], acc2[1], 0, 0, 0);
      __builtin_amdgcn_s_setprio(0);
      if (s + 2 < 16) {
        int g6 = (s + 2) * 4 + h;
        a2A = *(const bf16x8*)(Sx + sxr * 1024 + ((g6 ^ sx7) << 4));
        const unsigned char* pn2 = wB2 + (size_t)(s + 2) * 4096;
        cA[0] = *(const bf16x8*)(pn2);
        cA[1] = *(const bf16x8*)(pn2 + 1024);
      }
      __builtin_amdgcn_s_setprio(1);
      acc2[0] = __builtin_amdgcn_mfma_f32_16x16x32_bf16(a2B, cB[0], acc2[0], 0, 0, 0);
      acc2[1] = __builtin_amdgcn_mfma_f32_16x16x32_bf16(a2B, cB[1], acc2[1], 0, 0, 0);
      __builtin_amdgcn_s_setprio(0);
    }
    // C rows rvb..rvb+3 = positions (all 16 real at PPB=16)
    #pragma unroll
    for (int n = 0; n < 2; n++)
      #pragma unroll
      for (int v = 0; v < 4; v++)
        Ts[(rvb + v) * TSS + wid * 32 + n * 16 + co] = acc2[n][v];
  }
  __syncthreads();               // B2: Ts ready (cross-wave in epilogue)

  // ---- epilogue: residual from As (LDS), direct wide stores ----
  #pragma unroll
  for (int n = 0; n < 4; n++) {
    const int o = wn * 64 + n * 16 + co;
    const float C1 = c12[o];
    const float C2 = c12[KH + o];
    const int swzo = o >> 3;
    const int ob2 = (o & 7) * 2;
    #pragma unroll
    for (int m = 0; m < 3; m++) {
      int j0  = wm * 48 + m * 16 + rvb;
      int pl0 = j0 / 6;
      int d0  = j0 - pl0 * 6;
      float mean0 = st[2 * pl0], rstd0 = st[2 * pl0 + 1];
      float t20   = Ts[pl0 * TSS + o];
      float cc0   = C1 - mean0 * rstd0 * C2;
      if (d0 < 3) {
        f32x4 ov;
        #pragma unroll
        for (int v = 0; v < 4; v++) {
          int j = j0 + v;
          unsigned short rx = *(const unsigned short*)(
              As + j * 1024 + ((swzo ^ (j & 7)) << 4) + ob2);
          ov[v] = bf2f(rx) + fmaxf(rstd0 * (acc1[m][n][v] + t20) + cc0, 0.f);
        }
        *(f32x4*)(out + (r0 + pl0) * DF + o * 6 + d0) = ov;
      } else {                               // d0 == 4: split 2 + 2
        int pl1 = pl0 + 1;
        float mean1 = st[2 * pl1], rstd1 = st[2 * pl1 + 1];
        float t21   = Ts[pl1 * TSS + o];
        float cc1   = C1 - mean1 * rstd1 * C2;
        f32x2 o0, o1;
        #pragma unroll
        for (int v = 0; v < 2; v++) {
          int j = j0 + v;
          unsigned short rx = *(const unsigned short*)(
              As + j * 1024 + ((swzo ^ (j & 7)) << 4) + ob2);
          o0[v] = bf2f(rx) + fmaxf(rstd0 * (acc1[m][n][v] + t20) + cc0, 0.f);
        }
        #pragma unroll
        for (int v = 2; v < 4; v++) {
          int j = j0 + v;
          unsigned short rx = *(const unsigned short*)(
              As + j * 1024 + ((swzo ^ (j & 7)) << 4) + ob2);
          o1[v - 2] = bf2f(rx) + fmaxf(rstd1 * (acc1[m][n][v] + t21) + cc1, 0.f);
        }
        *(f32x2*)(out + (r0 + pl0) * DF + o * 6 + 4) = o0;
        *(f32x2*)(out + (r0 + pl1) * DF + o * 6)     = o1;
      }
    }
  }
}

extern "C" void kernel_launch(void* const* d_in, const int* in_sizes, int n_in,
                              void* d_out, int out_size, void* d_ws, size_t ws_size,
                              hipStream_t stream) {
  (void)n_in; (void)out_size; (void)ws_size;
  const float* x  = (const float*)d_in[0];
  const float* cw = (const float*)d_in[1];
  const float* cb = (const float*)d_in[2];
  const float* nw = (const float*)d_in[3];
  const float* nb = (const float*)d_in[4];
  float* out = (float*)d_out;

  unsigned char* wbt = (unsigned char*)d_ws;                    // 1 MB images
  float* c12 = (float*)((char*)d_ws + (size_t)1024 * 1024);     // 4 KB

  prep_w<<<512, 256, 0, stream>>>(cw, cb, nw, nb, wbt, c12);

  const int R = in_sizes[0] / DF;            // 24576 positions
  fused_main<<<R / PPB, 1024, 0, stream>>>(x, wbt, c12, out);
}